// Round 2
// baseline (125.738 us; speedup 1.0000x reference)
//
#include <hip/hip_runtime.h>
#include <math.h>

#define NQ 10
#define NPAR 100
#define FDIM 256
#define BATCH 256
#define NOUT 30
#define TWO_PI_F 6.283185307179586f

// State layout: amplitude index i (10 bits). Bits [9:6] -> register slot a (16 float2
// per lane), bits [5:0] -> lane. Wire w (PennyLane MSB-first) <-> bit (9 - w).

__device__ __forceinline__ float shx(float v, int mask) {
    return __shfl_xor(v, mask, 64);
}

// ---- fused 1-qubit gate U = Rz*Ry*Rx on bit BIT ----
template<int BIT>
__device__ __forceinline__ void gate1q(float2 (&st)[16], int lane,
                                       float2 u00, float2 u01, float2 u10, float2 u11)
{
    if constexpr (BIT >= 6) {
        constexpr int rb = 1 << (BIT - 6);
        #pragma unroll
        for (int a = 0; a < 16; ++a) {
            if (a & rb) continue;
            const int a1 = a | rb;
            const float2 A0 = st[a], A1 = st[a1];
            float2 n0, n1;
            n0.x = u00.x*A0.x - u00.y*A0.y + u01.x*A1.x - u01.y*A1.y;
            n0.y = u00.x*A0.y + u00.y*A0.x + u01.x*A1.y + u01.y*A1.x;
            n1.x = u10.x*A0.x - u10.y*A0.y + u11.x*A1.x - u11.y*A1.y;
            n1.y = u10.x*A0.y + u10.y*A0.x + u11.x*A1.y + u11.y*A1.x;
            st[a] = n0; st[a1] = n1;
        }
    } else {
        constexpr int lb = 1 << BIT;
        const bool hi = (lane & lb) != 0;
        // lane with bit=0 computes u00*mine + u01*partner; bit=1: u11*mine + u10*partner
        const float2 A = hi ? u11 : u00;
        const float2 B = hi ? u10 : u01;
        #pragma unroll
        for (int a = 0; a < 16; ++a) {
            const float2 m = st[a];
            float2 p;
            p.x = shx(m.x, lb); p.y = shx(m.y, lb);
            float2 n;
            n.x = A.x*m.x - A.y*m.y + B.x*p.x - B.y*p.y;
            n.y = A.x*m.y + A.y*m.x + B.x*p.y + B.y*p.x;
            st[a] = n;
        }
    }
}

// ---- CRX(theta) control bit BC, target bit BT; c=cos(t/2), s=sin(t/2) ----
// RX pair update (control==1): n0 = c*a0 - i s a1 ; n1 = c*a1 - i s a0  (symmetric)
template<int BC, int BT>
__device__ __forceinline__ void crx(float2 (&st)[16], int lane, float c, float s)
{
    if constexpr (BT >= 6) {
        constexpr int rt = 1 << (BT - 6);
        if constexpr (BC >= 6) {
            constexpr int rc = 1 << (BC - 6);
            #pragma unroll
            for (int a = 0; a < 16; ++a) {
                if (!(a & rc) || (a & rt)) continue;
                const int a1 = a | rt;
                const float2 A0 = st[a], A1 = st[a1];
                float2 n0, n1;
                n0.x = c*A0.x + s*A1.y;  n0.y = c*A0.y - s*A1.x;
                n1.x = c*A1.x + s*A0.y;  n1.y = c*A1.y - s*A0.x;
                st[a] = n0; st[a1] = n1;
            }
        } else {
            constexpr int lc = 1 << BC;
            const bool act = (lane & lc) != 0;
            const float cc = act ? c : 1.f;
            const float ss = act ? s : 0.f;
            #pragma unroll
            for (int a = 0; a < 16; ++a) {
                if (a & rt) continue;
                const int a1 = a | rt;
                const float2 A0 = st[a], A1 = st[a1];
                float2 n0, n1;
                n0.x = cc*A0.x + ss*A1.y;  n0.y = cc*A0.y - ss*A1.x;
                n1.x = cc*A1.x + ss*A0.y;  n1.y = cc*A1.y - ss*A0.x;
                st[a] = n0; st[a1] = n1;
            }
        }
    } else {
        constexpr int lt = 1 << BT;
        float cc, ss;
        if constexpr (BC < 6) {
            constexpr int lc = 1 << BC;
            const bool act = (lane & lc) != 0;
            cc = act ? c : 1.f;
            ss = act ? s : 0.f;
        } else { cc = c; ss = s; }
        #pragma unroll
        for (int a = 0; a < 16; ++a) {
            if constexpr (BC >= 6) {
                constexpr int rc = 1 << (BC - 6);
                if (!(a & rc)) continue;
            }
            const float2 m = st[a];
            float2 p;
            p.x = shx(m.x, lt); p.y = shx(m.y, lt);
            float2 n;
            n.x = cc*m.x + ss*p.y;
            n.y = cc*m.y - ss*p.x;
            st[a] = n;
        }
    }
}

// ---- recursive circuit drivers (compile-time q) ----
template<int Q>
__device__ __forceinline__ void layer1q(float2 (&st)[16], int lane, const float2* cs, int idx)
{
    if constexpr (Q < NQ) {
        const float2 X = cs[idx], Y = cs[idx + 1], Z = cs[idx + 2];
        const float cx = X.x, sx = X.y, cy = Y.x, sy = Y.y, cz = Z.x, sz = Z.y;
        // M = Ry*Rx ; U = Rz*M
        const float2 m00 = make_float2( cy*cx,  sy*sx);
        const float2 m01 = make_float2(-sy*cx, -cy*sx);
        const float2 m10 = make_float2( sy*cx, -cy*sx);
        const float2 m11 = make_float2( cy*cx, -sy*sx);
        const float2 u00 = make_float2(cz*m00.x + sz*m00.y, cz*m00.y - sz*m00.x);
        const float2 u01 = make_float2(cz*m01.x + sz*m01.y, cz*m01.y - sz*m01.x);
        const float2 u10 = make_float2(cz*m10.x - sz*m10.y, cz*m10.y + sz*m10.x);
        const float2 u11 = make_float2(cz*m11.x - sz*m11.y, cz*m11.y + sz*m11.x);
        gate1q<9 - Q>(st, lane, u00, u01, u10, u11);
        layer1q<Q + 1>(st, lane, cs, idx + 3);
    }
}

template<int Q>
__device__ __forceinline__ void ringF(float2 (&st)[16], int lane, const float2* cs, int idx)
{
    if constexpr (Q < NQ) {
        const float2 p = cs[idx];
        crx<9 - Q, 9 - ((Q + 1) % NQ)>(st, lane, p.x, p.y);
        ringF<Q + 1>(st, lane, cs, idx + 1);
    }
}

template<int Q>
__device__ __forceinline__ void ringB(float2 (&st)[16], int lane, const float2* cs, int idx)
{
    if constexpr (Q >= 0) {
        const float2 p = cs[idx];
        crx<9 - Q, 9 - ((Q + NQ - 1) % NQ)>(st, lane, p.x, p.y);
        ringB<Q - 1>(st, lane, cs, idx + 1);
    }
}

// ---- measurements ----
template<int W>
__device__ __forceinline__ void measureAll(const float2 (&st)[16], int lane, float* m_row)
{
    if constexpr (W < NQ) {
        constexpr int B = 9 - W;
        float sre = 0.f, smm = 0.f, szz = 0.f;
        if constexpr (B >= 6) {
            constexpr int rb = 1 << (B - 6);
            #pragma unroll
            for (int a = 0; a < 16; ++a) {
                if (a & rb) continue;
                const int a1 = a | rb;
                const float2 A0 = st[a], A1 = st[a1];
                sre += A0.x*A1.x + A0.y*A1.y;
                smm += A0.x*A1.y - A0.y*A1.x;
                szz += A0.x*A0.x + A0.y*A0.y - A1.x*A1.x - A1.y*A1.y;
            }
            sre *= 2.f; smm *= 2.f;       // X = 2Re, Y = 2Im, Z = szz
        } else {
            constexpr int lb = 1 << B;
            const float sgn = (lane & lb) ? -1.f : 1.f;
            #pragma unroll
            for (int a = 0; a < 16; ++a) {
                const float2 m = st[a];
                float2 p;
                p.x = shx(m.x, lb); p.y = shx(m.y, lb);
                sre += m.x*p.x + m.y*p.y;                       // lane-sum = 2*Sum(Re) = X
                smm += sgn * (m.x*p.y - m.y*p.x);               // lane-sum = 2*Sum(Im) = Y
                szz += sgn * (m.x*m.x + m.y*m.y - p.x*p.x - p.y*p.y);  // lane-sum = 2*Z
            }
            szz *= 0.5f;
        }
        #pragma unroll
        for (int off = 1; off < 64; off <<= 1) {
            sre += shx(sre, off);
            smm += shx(smm, off);
            szz += shx(szz, off);
        }
        if (lane == 0) {
            m_row[W]      = sre;
            m_row[10 + W] = smm;
            m_row[20 + W] = szz;
        }
        measureAll<W + 1>(st, lane, m_row);
    }
}

__global__ __launch_bounds__(64) void qsb_branch(
    const float* __restrict__ x,
    const float* __restrict__ W1, const float* __restrict__ b1, const float* __restrict__ base1,
    const float* __restrict__ W2, const float* __restrict__ b2, const float* __restrict__ base2,
    const float* __restrict__ W3, const float* __restrict__ b3, const float* __restrict__ base3,
    float* __restrict__ m_ws)
{
    const int sim  = blockIdx.x;       // 0..767
    const int b    = sim & (BATCH - 1);
    const int br   = sim >> 8;
    const int lane = threadIdx.x;

    const float* W    = (br == 0) ? W1    : (br == 1) ? W2    : W3;
    const float* bias = (br == 0) ? b1    : (br == 1) ? b2    : b3;
    const float* base = (br == 0) ? base1 : (br == 1) ? base2 : base3;

    __shared__ float2 cs[NPAR];

    // ---- params: p = sigmoid(x.W^T + bias + base) * 2pi ; store (cos,sin)(p/2) ----
    if (lane < 50) {
        const int p0 = 2 * lane;
        const float4* xr = reinterpret_cast<const float4*>(x + (size_t)b * FDIM);
        const float4* w0 = reinterpret_cast<const float4*>(W + (size_t)p0 * FDIM);
        const float4* w1 = reinterpret_cast<const float4*>(W + (size_t)(p0 + 1) * FDIM);
        float acc0 = 0.f, acc1 = 0.f;
        #pragma unroll 8
        for (int k = 0; k < FDIM / 4; ++k) {
            const float4 xv = xr[k];          // wave-uniform -> scalar loads
            const float4 a  = w0[k];
            const float4 bb = w1[k];
            acc0 += xv.x*a.x  + xv.y*a.y  + xv.z*a.z  + xv.w*a.w;
            acc1 += xv.x*bb.x + xv.y*bb.y + xv.z*bb.z + xv.w*bb.w;
        }
        acc0 += bias[p0]     + base[p0];
        acc1 += bias[p0 + 1] + base[p0 + 1];
        const float t0 = TWO_PI_F / (1.f + __expf(-acc0));
        const float t1 = TWO_PI_F / (1.f + __expf(-acc1));
        float s0, c0, s1, c1;
        __sincosf(0.5f * t0, &s0, &c0);
        __sincosf(0.5f * t1, &s1, &c1);
        cs[p0]     = make_float2(c0, s0);
        cs[p0 + 1] = make_float2(c1, s1);
    }
    __syncthreads();

    // ---- init |0...0> ----
    float2 st[16];
    #pragma unroll
    for (int a = 0; a < 16; ++a) st[a] = make_float2(0.f, 0.f);
    if (lane == 0) st[0].x = 1.f;

    // ---- circuit: 2 layers of (1q sweep, forward CRX ring, backward CRX ring) ----
    layer1q<0>(st, lane, cs, 0);
    ringF<0>(st, lane, cs, 30);
    ringB<NQ - 1>(st, lane, cs, 40);
    layer1q<0>(st, lane, cs, 50);
    ringF<0>(st, lane, cs, 80);
    ringB<NQ - 1>(st, lane, cs, 90);

    // ---- measurements ----
    float* m_row = m_ws + ((size_t)br * BATCH + b) * NOUT;
    measureAll<0>(st, lane, m_row);
}

__global__ __launch_bounds__(256) void qsb_combine(
    const float* __restrict__ m,
    const float* __restrict__ ar_, const float* __restrict__ ai_,
    const float* __restrict__ br_, const float* __restrict__ bi_,
    const float* __restrict__ gr_, const float* __restrict__ gi_,
    float* __restrict__ out)
{
    const int i = blockIdx.x * blockDim.x + threadIdx.x;
    if (i >= BATCH * NOUT) return;
    const float ar = ar_[0], ai = ai_[0];
    const float br = br_[0], bi = bi_[0];
    const float gr = gr_[0], gi = gi_[0];
    const float inv = 1.f / sqrtf(ar*ar + ai*ai + br*br + bi*bi + gr*gr + gi*gi + 1e-9f);
    const float m1 = m[i];
    const float m2 = m[BATCH * NOUT + i];
    const float m3 = m[2 * BATCH * NOUT + i];
    const float re = (ar * m1 + br * m2 + gr * m3) * inv;
    const float im = (ai * m1 + bi * m2 + gi * m3) * inv;
    out[i] = sqrtf(re * re + im * im);
}

extern "C" void kernel_launch(void* const* d_in, const int* in_sizes, int n_in,
                              void* d_out, int out_size, void* d_ws, size_t ws_size,
                              hipStream_t stream)
{
    (void)in_sizes; (void)n_in; (void)out_size; (void)ws_size;
    const float* x     = (const float*)d_in[0];
    const float* W1    = (const float*)d_in[1];
    const float* b1    = (const float*)d_in[2];
    const float* W2    = (const float*)d_in[3];
    const float* b2    = (const float*)d_in[4];
    const float* W3    = (const float*)d_in[5];
    const float* b3    = (const float*)d_in[6];
    const float* base1 = (const float*)d_in[7];
    const float* base2 = (const float*)d_in[8];
    const float* base3 = (const float*)d_in[9];
    const float* ar    = (const float*)d_in[10];
    const float* ai    = (const float*)d_in[11];
    const float* br    = (const float*)d_in[12];
    const float* bi    = (const float*)d_in[13];
    const float* gr    = (const float*)d_in[14];
    const float* gi    = (const float*)d_in[15];

    float* m_ws = (float*)d_ws;          // 3 * 256 * 30 floats
    float* out  = (float*)d_out;

    qsb_branch<<<dim3(BATCH * 3), dim3(64), 0, stream>>>(
        x, W1, b1, base1, W2, b2, base2, W3, b3, base3, m_ws);
    qsb_combine<<<(BATCH * NOUT + 255) / 256, 256, 0, stream>>>(
        m_ws, ar, ai, br, bi, gr, gi, out);
}

// Round 3
// 121.679 us; speedup vs baseline: 1.0334x; 1.0334x over previous
//
#include <hip/hip_runtime.h>
#include <math.h>

#define NQ 10
#define NPAR 100
#define FDIM 256
#define BATCH 256
#define NOUT 30
#define TWO_PI_F 6.283185307179586f

// State layout: amplitude index i (10 bits). Bits [9:6] -> register slot a (16 float2
// per lane), bits [5:0] -> lane. Wire w (PennyLane MSB-first) <-> bit (9 - w).
//
// KEY STRUCTURE (round 3): every shuffle-based gate is two-phase —
//   phase 1: gather all partner components into p[16] (32 independent ds_swizzle)
//   phase 2: compute. This lets the compiler issue all swizzles before one waitcnt
// instead of a serial shuffle->wait->use chain (round 2 was latency-bound on that).

__device__ __forceinline__ float shx(float v, int mask) {
    return __shfl_xor(v, mask, 64);
}

__device__ __forceinline__ float2 cmul(float2 a, float2 b) {
    return make_float2(a.x*b.x - a.y*b.y, a.x*b.y + a.y*b.x);
}

// ---- fused 1-qubit gate U = Rz*Ry*Rx on bit BIT ----
template<int BIT>
__device__ __forceinline__ void gate1q(float2 (&st)[16], int lane,
                                       float2 u00, float2 u01, float2 u10, float2 u11)
{
    if constexpr (BIT >= 6) {
        constexpr int rb = 1 << (BIT - 6);
        #pragma unroll
        for (int a = 0; a < 16; ++a) {
            if (a & rb) continue;
            const int a1 = a | rb;
            const float2 A0 = st[a], A1 = st[a1];
            float2 n0, n1;
            n0.x = u00.x*A0.x - u00.y*A0.y + u01.x*A1.x - u01.y*A1.y;
            n0.y = u00.x*A0.y + u00.y*A0.x + u01.x*A1.y + u01.y*A1.x;
            n1.x = u10.x*A0.x - u10.y*A0.y + u11.x*A1.x - u11.y*A1.y;
            n1.y = u10.x*A0.y + u10.y*A0.x + u11.x*A1.y + u11.y*A1.x;
            st[a] = n0; st[a1] = n1;
        }
    } else {
        constexpr int lb = 1 << BIT;
        float2 p[16];
        #pragma unroll
        for (int a = 0; a < 16; ++a) {          // phase 1: batched gather
            p[a].x = shx(st[a].x, lb);
            p[a].y = shx(st[a].y, lb);
        }
        const bool hi = (lane & lb) != 0;
        const float2 A = hi ? u11 : u00;
        const float2 B = hi ? u10 : u01;
        #pragma unroll
        for (int a = 0; a < 16; ++a) {          // phase 2: compute
            const float2 m = st[a];
            float2 n;
            n.x = A.x*m.x - A.y*m.y + B.x*p[a].x - B.y*p[a].y;
            n.y = A.x*m.y + A.y*m.x + B.x*p[a].y + B.y*p[a].x;
            st[a] = n;
        }
    }
}

// ---- CRX(theta) control bit BC, target bit BT; c=cos(t/2), s=sin(t/2) ----
template<int BC, int BT>
__device__ __forceinline__ void crx(float2 (&st)[16], int lane, float c, float s)
{
    if constexpr (BT >= 6) {
        constexpr int rt = 1 << (BT - 6);
        if constexpr (BC >= 6) {
            constexpr int rc = 1 << (BC - 6);
            #pragma unroll
            for (int a = 0; a < 16; ++a) {
                if (!(a & rc) || (a & rt)) continue;
                const int a1 = a | rt;
                const float2 A0 = st[a], A1 = st[a1];
                float2 n0, n1;
                n0.x = c*A0.x + s*A1.y;  n0.y = c*A0.y - s*A1.x;
                n1.x = c*A1.x + s*A0.y;  n1.y = c*A1.y - s*A0.x;
                st[a] = n0; st[a1] = n1;
            }
        } else {
            constexpr int lc = 1 << BC;
            const bool act = (lane & lc) != 0;
            const float cc = act ? c : 1.f;
            const float ss = act ? s : 0.f;
            #pragma unroll
            for (int a = 0; a < 16; ++a) {
                if (a & rt) continue;
                const int a1 = a | rt;
                const float2 A0 = st[a], A1 = st[a1];
                float2 n0, n1;
                n0.x = cc*A0.x + ss*A1.y;  n0.y = cc*A0.y - ss*A1.x;
                n1.x = cc*A1.x + ss*A0.y;  n1.y = cc*A1.y - ss*A0.x;
                st[a] = n0; st[a1] = n1;
            }
        }
    } else {
        constexpr int lt = 1 << BT;
        float cc, ss;
        if constexpr (BC < 6) {
            constexpr int lc = 1 << BC;
            const bool act = (lane & lc) != 0;
            cc = act ? c : 1.f;
            ss = act ? s : 0.f;
        } else { cc = c; ss = s; }
        float2 p[16];
        #pragma unroll
        for (int a = 0; a < 16; ++a) {          // phase 1: batched gather
            if constexpr (BC >= 6) { if (!(a & (1 << (BC - 6)))) continue; }
            p[a].x = shx(st[a].x, lt);
            p[a].y = shx(st[a].y, lt);
        }
        #pragma unroll
        for (int a = 0; a < 16; ++a) {          // phase 2: compute
            if constexpr (BC >= 6) { if (!(a & (1 << (BC - 6)))) continue; }
            float2 n;
            n.x = cc*st[a].x + ss*p[a].y;
            n.y = cc*st[a].y - ss*p[a].x;
            st[a] = n;
        }
    }
}

// ---- recursive circuit drivers (compile-time q) ----
template<int Q>
__device__ __forceinline__ void layer1q(float2 (&st)[16], int lane, const float2* cs, int idx)
{
    if constexpr (Q < NQ) {
        const float2 X = cs[idx], Y = cs[idx + 1], Z = cs[idx + 2];
        const float cx = X.x, sx = X.y, cy = Y.x, sy = Y.y, cz = Z.x, sz = Z.y;
        const float2 m00 = make_float2( cy*cx,  sy*sx);
        const float2 m01 = make_float2(-sy*cx, -cy*sx);
        const float2 m10 = make_float2( sy*cx, -cy*sx);
        const float2 m11 = make_float2( cy*cx, -sy*sx);
        const float2 u00 = make_float2(cz*m00.x + sz*m00.y, cz*m00.y - sz*m00.x);
        const float2 u01 = make_float2(cz*m01.x + sz*m01.y, cz*m01.y - sz*m01.x);
        const float2 u10 = make_float2(cz*m10.x - sz*m10.y, cz*m10.y + sz*m10.x);
        const float2 u11 = make_float2(cz*m11.x - sz*m11.y, cz*m11.y + sz*m11.x);
        gate1q<9 - Q>(st, lane, u00, u01, u10, u11);
        layer1q<Q + 1>(st, lane, cs, idx + 3);
    }
}

template<int Q>
__device__ __forceinline__ void ringF(float2 (&st)[16], int lane, const float2* cs, int idx)
{
    if constexpr (Q < NQ) {
        const float2 p = cs[idx];
        crx<9 - Q, 9 - ((Q + 1) % NQ)>(st, lane, p.x, p.y);
        ringF<Q + 1>(st, lane, cs, idx + 1);
    }
}

template<int Q>
__device__ __forceinline__ void ringB(float2 (&st)[16], int lane, const float2* cs, int idx)
{
    if constexpr (Q >= 0) {
        const float2 p = cs[idx];
        crx<9 - Q, 9 - ((Q + NQ - 1) % NQ)>(st, lane, p.x, p.y);
        ringB<Q - 1>(st, lane, cs, idx + 1);
    }
}

// ---- column 0 of fused U = Rz*Ry*Rx (for product-state init of sweep 1) ----
__device__ __forceinline__ void col0(const float2* cs, int w, float2& u00, float2& u10)
{
    const float2 X = cs[3*w], Y = cs[3*w + 1], Z = cs[3*w + 2];
    const float cx = X.x, sx = X.y, cy = Y.x, sy = Y.y, cz = Z.x, sz = Z.y;
    const float2 m00 = make_float2(cy*cx,  sy*sx);
    const float2 m10 = make_float2(sy*cx, -cy*sx);
    u00 = make_float2(cz*m00.x + sz*m00.y, cz*m00.y - sz*m00.x);   // (cz,-sz)*m00
    u10 = make_float2(cz*m10.x - sz*m10.y, cz*m10.y + sz*m10.x);   // (cz, sz)*m10
}

// ---- measurement partials (batched shuffles per wire) ----
template<int W>
__device__ __forceinline__ void measurePartials(const float2 (&st)[16], int lane,
                                                float (&vx)[10], float (&vy)[10], float (&vz)[10])
{
    if constexpr (W < NQ) {
        constexpr int B = 9 - W;
        float sre = 0.f, smm = 0.f, szz = 0.f;
        if constexpr (B >= 6) {
            constexpr int rb = 1 << (B - 6);
            #pragma unroll
            for (int a = 0; a < 16; ++a) {
                if (a & rb) continue;
                const int a1 = a | rb;
                const float2 A0 = st[a], A1 = st[a1];
                sre += A0.x*A1.x + A0.y*A1.y;
                smm += A0.x*A1.y - A0.y*A1.x;
                szz += A0.x*A0.x + A0.y*A0.y - A1.x*A1.x - A1.y*A1.y;
            }
            sre *= 2.f; smm *= 2.f;
        } else {
            constexpr int lb = 1 << B;
            float2 p[16];
            #pragma unroll
            for (int a = 0; a < 16; ++a) {
                p[a].x = shx(st[a].x, lb);
                p[a].y = shx(st[a].y, lb);
            }
            const float sgn = (lane & lb) ? -1.f : 1.f;
            #pragma unroll
            for (int a = 0; a < 16; ++a) {
                const float2 m = st[a];
                sre += m.x*p[a].x + m.y*p[a].y;
                smm += sgn * (m.x*p[a].y - m.y*p[a].x);
                szz += sgn * (m.x*m.x + m.y*m.y - p[a].x*p[a].x - p[a].y*p[a].y);
            }
            szz *= 0.5f;
        }
        vx[W] = sre; vy[W] = smm; vz[W] = szz;
        measurePartials<W + 1>(st, lane, vx, vy, vz);
    }
}

__global__ __launch_bounds__(64) void qsb_branch(
    const float* __restrict__ x,
    const float* __restrict__ W1, const float* __restrict__ b1, const float* __restrict__ base1,
    const float* __restrict__ W2, const float* __restrict__ b2, const float* __restrict__ base2,
    const float* __restrict__ W3, const float* __restrict__ b3, const float* __restrict__ base3,
    float* __restrict__ m_ws)
{
    const int sim  = blockIdx.x;       // 0..767
    const int b    = sim & (BATCH - 1);
    const int br   = sim >> 8;
    const int lane = threadIdx.x;

    const float* W    = (br == 0) ? W1    : (br == 1) ? W2    : W3;
    const float* bias = (br == 0) ? b1    : (br == 1) ? b2    : b3;
    const float* base = (br == 0) ? base1 : (br == 1) ? base2 : base3;

    __shared__ float2 cs[NPAR];

    // ---- params: p = sigmoid(x.W^T + bias + base) * 2pi ; store (cos,sin)(p/2) ----
    if (lane < 50) {
        const int p0 = 2 * lane;
        const float4* xr = reinterpret_cast<const float4*>(x + (size_t)b * FDIM);
        const float4* w0 = reinterpret_cast<const float4*>(W + (size_t)p0 * FDIM);
        const float4* w1 = reinterpret_cast<const float4*>(W + (size_t)(p0 + 1) * FDIM);
        float acc0 = 0.f, acc1 = 0.f;
        #pragma unroll 16
        for (int k = 0; k < FDIM / 4; ++k) {
            const float4 xv = xr[k];
            const float4 a  = w0[k];
            const float4 bb = w1[k];
            acc0 += xv.x*a.x  + xv.y*a.y  + xv.z*a.z  + xv.w*a.w;
            acc1 += xv.x*bb.x + xv.y*bb.y + xv.z*bb.z + xv.w*bb.w;
        }
        acc0 += bias[p0]     + base[p0];
        acc1 += bias[p0 + 1] + base[p0 + 1];
        const float t0 = TWO_PI_F / (1.f + __expf(-acc0));
        const float t1 = TWO_PI_F / (1.f + __expf(-acc1));
        float s0, c0, s1, c1;
        __sincosf(0.5f * t0, &s0, &c0);
        __sincosf(0.5f * t1, &s1, &c1);
        cs[p0]     = make_float2(c0, s0);
        cs[p0 + 1] = make_float2(c1, s1);
    }
    __syncthreads();

    // ---- sweep 1 folded into product-state init: amp(i) = prod_q (U_q col 0)[bit_q(i)] ----
    float2 st[16];
    {
        float2 lp = make_float2(1.f, 0.f);
        #pragma unroll
        for (int bb = 0; bb < 6; ++bb) {            // lane bits: wire 9-bb
            float2 u00, u10;
            col0(cs, 9 - bb, u00, u10);
            const float2 sel = ((lane >> bb) & 1) ? u10 : u00;
            lp = cmul(lp, sel);
        }
        float2 v3[2], v2[2], v1[2], v0[2];          // reg bits 6..9: wires 3,2,1,0
        col0(cs, 3, v3[0], v3[1]);
        col0(cs, 2, v2[0], v2[1]);
        col0(cs, 1, v1[0], v1[1]);
        col0(cs, 0, v0[0], v0[1]);
        #pragma unroll
        for (int a = 0; a < 16; ++a) {
            float2 t = cmul(v3[a & 1], v2[(a >> 1) & 1]);
            t = cmul(t, cmul(v1[(a >> 2) & 1], v0[(a >> 3) & 1]));
            st[a] = cmul(t, lp);
        }
    }

    // ---- circuit (sweep 1 already folded) ----
    ringF<0>(st, lane, cs, 30);
    ringB<NQ - 1>(st, lane, cs, 40);
    layer1q<0>(st, lane, cs, 50);
    ringF<0>(st, lane, cs, 80);
    ringB<NQ - 1>(st, lane, cs, 90);

    // ---- measurements: partials, then one batched 30-wide butterfly ----
    float vx[10], vy[10], vz[10];
    measurePartials<0>(st, lane, vx, vy, vz);

    #pragma unroll
    for (int off = 1; off < 64; off <<= 1) {
        #pragma unroll
        for (int w = 0; w < 10; ++w) {
            vx[w] += shx(vx[w], off);
            vy[w] += shx(vy[w], off);
            vz[w] += shx(vz[w], off);
        }
    }

    if (lane == 0) {
        float* m_row = m_ws + ((size_t)br * BATCH + b) * NOUT;
        #pragma unroll
        for (int w = 0; w < 10; ++w) {
            m_row[w]      = vx[w];
            m_row[10 + w] = vy[w];
            m_row[20 + w] = vz[w];
        }
    }
}

__global__ __launch_bounds__(256) void qsb_combine(
    const float* __restrict__ m,
    const float* __restrict__ ar_, const float* __restrict__ ai_,
    const float* __restrict__ br_, const float* __restrict__ bi_,
    const float* __restrict__ gr_, const float* __restrict__ gi_,
    float* __restrict__ out)
{
    const int i = blockIdx.x * blockDim.x + threadIdx.x;
    if (i >= BATCH * NOUT) return;
    const float ar = ar_[0], ai = ai_[0];
    const float br = br_[0], bi = bi_[0];
    const float gr = gr_[0], gi = gi_[0];
    const float inv = 1.f / sqrtf(ar*ar + ai*ai + br*br + bi*bi + gr*gr + gi*gi + 1e-9f);
    const float m1 = m[i];
    const float m2 = m[BATCH * NOUT + i];
    const float m3 = m[2 * BATCH * NOUT + i];
    const float re = (ar * m1 + br * m2 + gr * m3) * inv;
    const float im = (ai * m1 + bi * m2 + gi * m3) * inv;
    out[i] = sqrtf(re * re + im * im);
}

extern "C" void kernel_launch(void* const* d_in, const int* in_sizes, int n_in,
                              void* d_out, int out_size, void* d_ws, size_t ws_size,
                              hipStream_t stream)
{
    (void)in_sizes; (void)n_in; (void)out_size; (void)ws_size;
    const float* x     = (const float*)d_in[0];
    const float* W1    = (const float*)d_in[1];
    const float* b1    = (const float*)d_in[2];
    const float* W2    = (const float*)d_in[3];
    const float* b2    = (const float*)d_in[4];
    const float* W3    = (const float*)d_in[5];
    const float* b3    = (const float*)d_in[6];
    const float* base1 = (const float*)d_in[7];
    const float* base2 = (const float*)d_in[8];
    const float* base3 = (const float*)d_in[9];
    const float* ar    = (const float*)d_in[10];
    const float* ai    = (const float*)d_in[11];
    const float* br    = (const float*)d_in[12];
    const float* bi    = (const float*)d_in[13];
    const float* gr    = (const float*)d_in[14];
    const float* gi    = (const float*)d_in[15];

    float* m_ws = (float*)d_ws;          // 3 * 256 * 30 floats
    float* out  = (float*)d_out;

    qsb_branch<<<dim3(BATCH * 3), dim3(64), 0, stream>>>(
        x, W1, b1, base1, W2, b2, base2, W3, b3, base3, m_ws);
    qsb_combine<<<(BATCH * NOUT + 255) / 256, 256, 0, stream>>>(
        m_ws, ar, ai, br, bi, gr, gi, out);
}

// Round 4
// 117.279 us; speedup vs baseline: 1.0721x; 1.0375x over previous
//
#include <hip/hip_runtime.h>
#include <math.h>

#define NQ 10
#define NPAR 100
#define FDIM 256
#define BATCH 256
#define NOUT 30
#define TWO_PI_F 6.283185307179586f

// State layout: amplitude index i (10 bits). Bits [9:6] -> register slot a (16 float2
// per lane), bits [5:0] -> lane. Wire w (PennyLane MSB-first) <-> bit (9 - w).
// Round 4: single fused kernel. One block per batch item, 3 waves = 3 branches.
// Gate code is the round-2 version verbatim (measured 43 us; round-3 batched
// variant regressed to 100 us). First 1q sweep folded into product-state init.

__device__ __forceinline__ float shx(float v, int mask) {
    return __shfl_xor(v, mask, 64);
}

__device__ __forceinline__ float2 cmul(float2 a, float2 b) {
    return make_float2(a.x*b.x - a.y*b.y, a.x*b.y + a.y*b.x);
}

// ---- fused 1-qubit gate U = Rz*Ry*Rx on bit BIT (round-2 code) ----
template<int BIT>
__device__ __forceinline__ void gate1q(float2 (&st)[16], int lane,
                                       float2 u00, float2 u01, float2 u10, float2 u11)
{
    if constexpr (BIT >= 6) {
        constexpr int rb = 1 << (BIT - 6);
        #pragma unroll
        for (int a = 0; a < 16; ++a) {
            if (a & rb) continue;
            const int a1 = a | rb;
            const float2 A0 = st[a], A1 = st[a1];
            float2 n0, n1;
            n0.x = u00.x*A0.x - u00.y*A0.y + u01.x*A1.x - u01.y*A1.y;
            n0.y = u00.x*A0.y + u00.y*A0.x + u01.x*A1.y + u01.y*A1.x;
            n1.x = u10.x*A0.x - u10.y*A0.y + u11.x*A1.x - u11.y*A1.y;
            n1.y = u10.x*A0.y + u10.y*A0.x + u11.x*A1.y + u11.y*A1.x;
            st[a] = n0; st[a1] = n1;
        }
    } else {
        constexpr int lb = 1 << BIT;
        const bool hi = (lane & lb) != 0;
        const float2 A = hi ? u11 : u00;
        const float2 B = hi ? u10 : u01;
        #pragma unroll
        for (int a = 0; a < 16; ++a) {
            const float2 m = st[a];
            float2 p;
            p.x = shx(m.x, lb); p.y = shx(m.y, lb);
            float2 n;
            n.x = A.x*m.x - A.y*m.y + B.x*p.x - B.y*p.y;
            n.y = A.x*m.y + A.y*m.x + B.x*p.y + B.y*p.x;
            st[a] = n;
        }
    }
}

// ---- CRX(theta) control bit BC, target bit BT (round-2 code) ----
template<int BC, int BT>
__device__ __forceinline__ void crx(float2 (&st)[16], int lane, float c, float s)
{
    if constexpr (BT >= 6) {
        constexpr int rt = 1 << (BT - 6);
        if constexpr (BC >= 6) {
            constexpr int rc = 1 << (BC - 6);
            #pragma unroll
            for (int a = 0; a < 16; ++a) {
                if (!(a & rc) || (a & rt)) continue;
                const int a1 = a | rt;
                const float2 A0 = st[a], A1 = st[a1];
                float2 n0, n1;
                n0.x = c*A0.x + s*A1.y;  n0.y = c*A0.y - s*A1.x;
                n1.x = c*A1.x + s*A0.y;  n1.y = c*A1.y - s*A0.x;
                st[a] = n0; st[a1] = n1;
            }
        } else {
            constexpr int lc = 1 << BC;
            const bool act = (lane & lc) != 0;
            const float cc = act ? c : 1.f;
            const float ss = act ? s : 0.f;
            #pragma unroll
            for (int a = 0; a < 16; ++a) {
                if (a & rt) continue;
                const int a1 = a | rt;
                const float2 A0 = st[a], A1 = st[a1];
                float2 n0, n1;
                n0.x = cc*A0.x + ss*A1.y;  n0.y = cc*A0.y - ss*A1.x;
                n1.x = cc*A1.x + ss*A0.y;  n1.y = cc*A1.y - ss*A0.x;
                st[a] = n0; st[a1] = n1;
            }
        }
    } else {
        constexpr int lt = 1 << BT;
        float cc, ss;
        if constexpr (BC < 6) {
            constexpr int lc = 1 << BC;
            const bool act = (lane & lc) != 0;
            cc = act ? c : 1.f;
            ss = act ? s : 0.f;
        } else { cc = c; ss = s; }
        #pragma unroll
        for (int a = 0; a < 16; ++a) {
            if constexpr (BC >= 6) {
                constexpr int rc = 1 << (BC - 6);
                if (!(a & rc)) continue;
            }
            const float2 m = st[a];
            float2 p;
            p.x = shx(m.x, lt); p.y = shx(m.y, lt);
            float2 n;
            n.x = cc*m.x + ss*p.y;
            n.y = cc*m.y - ss*p.x;
            st[a] = n;
        }
    }
}

// ---- recursive circuit drivers (compile-time q) ----
template<int Q>
__device__ __forceinline__ void layer1q(float2 (&st)[16], int lane, const float2* cs, int idx)
{
    if constexpr (Q < NQ) {
        const float2 X = cs[idx], Y = cs[idx + 1], Z = cs[idx + 2];
        const float cx = X.x, sx = X.y, cy = Y.x, sy = Y.y, cz = Z.x, sz = Z.y;
        const float2 m00 = make_float2( cy*cx,  sy*sx);
        const float2 m01 = make_float2(-sy*cx, -cy*sx);
        const float2 m10 = make_float2( sy*cx, -cy*sx);
        const float2 m11 = make_float2( cy*cx, -sy*sx);
        const float2 u00 = make_float2(cz*m00.x + sz*m00.y, cz*m00.y - sz*m00.x);
        const float2 u01 = make_float2(cz*m01.x + sz*m01.y, cz*m01.y - sz*m01.x);
        const float2 u10 = make_float2(cz*m10.x - sz*m10.y, cz*m10.y + sz*m10.x);
        const float2 u11 = make_float2(cz*m11.x - sz*m11.y, cz*m11.y + sz*m11.x);
        gate1q<9 - Q>(st, lane, u00, u01, u10, u11);
        layer1q<Q + 1>(st, lane, cs, idx + 3);
    }
}

template<int Q>
__device__ __forceinline__ void ringF(float2 (&st)[16], int lane, const float2* cs, int idx)
{
    if constexpr (Q < NQ) {
        const float2 p = cs[idx];
        crx<9 - Q, 9 - ((Q + 1) % NQ)>(st, lane, p.x, p.y);
        ringF<Q + 1>(st, lane, cs, idx + 1);
    }
}

template<int Q>
__device__ __forceinline__ void ringB(float2 (&st)[16], int lane, const float2* cs, int idx)
{
    if constexpr (Q >= 0) {
        const float2 p = cs[idx];
        crx<9 - Q, 9 - ((Q + NQ - 1) % NQ)>(st, lane, p.x, p.y);
        ringB<Q - 1>(st, lane, cs, idx + 1);
    }
}

// ---- column 0 of fused U = Rz*Ry*Rx (product-state init; verified round 3) ----
__device__ __forceinline__ void col0(const float2* cs, int w, float2& u00, float2& u10)
{
    const float2 X = cs[3*w], Y = cs[3*w + 1], Z = cs[3*w + 2];
    const float cx = X.x, sx = X.y, cy = Y.x, sy = Y.y, cz = Z.x, sz = Z.y;
    const float2 m00 = make_float2(cy*cx,  sy*sx);
    const float2 m10 = make_float2(sy*cx, -cy*sx);
    u00 = make_float2(cz*m00.x + sz*m00.y, cz*m00.y - sz*m00.x);
    u10 = make_float2(cz*m10.x - sz*m10.y, cz*m10.y + sz*m10.x);
}

// ---- measurements (round-2 code, writes to per-wave LDS row) ----
template<int W>
__device__ __forceinline__ void measureAll(const float2 (&st)[16], int lane, float* m_row)
{
    if constexpr (W < NQ) {
        constexpr int B = 9 - W;
        float sre = 0.f, smm = 0.f, szz = 0.f;
        if constexpr (B >= 6) {
            constexpr int rb = 1 << (B - 6);
            #pragma unroll
            for (int a = 0; a < 16; ++a) {
                if (a & rb) continue;
                const int a1 = a | rb;
                const float2 A0 = st[a], A1 = st[a1];
                sre += A0.x*A1.x + A0.y*A1.y;
                smm += A0.x*A1.y - A0.y*A1.x;
                szz += A0.x*A0.x + A0.y*A0.y - A1.x*A1.x - A1.y*A1.y;
            }
            sre *= 2.f; smm *= 2.f;
        } else {
            constexpr int lb = 1 << B;
            const float sgn = (lane & lb) ? -1.f : 1.f;
            #pragma unroll
            for (int a = 0; a < 16; ++a) {
                const float2 m = st[a];
                float2 p;
                p.x = shx(m.x, lb); p.y = shx(m.y, lb);
                sre += m.x*p.x + m.y*p.y;
                smm += sgn * (m.x*p.y - m.y*p.x);
                szz += sgn * (m.x*m.x + m.y*m.y - p.x*p.x - p.y*p.y);
            }
            szz *= 0.5f;
        }
        #pragma unroll
        for (int off = 1; off < 64; off <<= 1) {
            sre += shx(sre, off);
            smm += shx(smm, off);
            szz += shx(szz, off);
        }
        if (lane == 0) {
            m_row[W]      = sre;
            m_row[10 + W] = smm;
            m_row[20 + W] = szz;
        }
        measureAll<W + 1>(st, lane, m_row);
    }
}

__global__ __launch_bounds__(192) void qsb_fused(
    const float* __restrict__ x,
    const float* __restrict__ W1, const float* __restrict__ b1, const float* __restrict__ base1,
    const float* __restrict__ W2, const float* __restrict__ b2, const float* __restrict__ base2,
    const float* __restrict__ W3, const float* __restrict__ b3, const float* __restrict__ base3,
    const float* __restrict__ ar_, const float* __restrict__ ai_,
    const float* __restrict__ br_, const float* __restrict__ bi_,
    const float* __restrict__ gr_, const float* __restrict__ gi_,
    float* __restrict__ out)
{
    const int b    = blockIdx.x;             // batch item
    const int wv   = threadIdx.x >> 6;       // branch 0..2 (one wave each)
    const int lane = threadIdx.x & 63;

    const float* W    = (wv == 0) ? W1    : (wv == 1) ? W2    : W3;
    const float* bias = (wv == 0) ? b1    : (wv == 1) ? b2    : b3;
    const float* base = (wv == 0) ? base1 : (wv == 1) ? base2 : base3;

    __shared__ float2 css[3][NPAR];
    __shared__ float  mloc[3][NOUT];
    float2* cs = css[wv];

    // ---- params: p = sigmoid(x.W^T + bias + base) * 2pi ; store (cos,sin)(p/2) ----
    if (lane < 50) {
        const int p0 = 2 * lane;
        const float4* xr = reinterpret_cast<const float4*>(x + (size_t)b * FDIM);
        const float4* w0 = reinterpret_cast<const float4*>(W + (size_t)p0 * FDIM);
        const float4* w1 = reinterpret_cast<const float4*>(W + (size_t)(p0 + 1) * FDIM);
        float acc0 = 0.f, acc1 = 0.f;
        #pragma unroll 8
        for (int k = 0; k < FDIM / 4; ++k) {
            const float4 xv = xr[k];
            const float4 a  = w0[k];
            const float4 bb = w1[k];
            acc0 += xv.x*a.x  + xv.y*a.y  + xv.z*a.z  + xv.w*a.w;
            acc1 += xv.x*bb.x + xv.y*bb.y + xv.z*bb.z + xv.w*bb.w;
        }
        acc0 += bias[p0]     + base[p0];
        acc1 += bias[p0 + 1] + base[p0 + 1];
        const float t0 = TWO_PI_F / (1.f + __expf(-acc0));
        const float t1 = TWO_PI_F / (1.f + __expf(-acc1));
        float s0, c0, s1, c1;
        __sincosf(0.5f * t0, &s0, &c0);
        __sincosf(0.5f * t1, &s1, &c1);
        cs[p0]     = make_float2(c0, s0);
        cs[p0 + 1] = make_float2(c1, s1);
    }
    __syncthreads();

    // ---- sweep 1 folded into product-state init ----
    float2 st[16];
    {
        float2 lp = make_float2(1.f, 0.f);
        #pragma unroll
        for (int bb = 0; bb < 6; ++bb) {            // lane bit bb <-> wire 9-bb
            float2 u00, u10;
            col0(cs, 9 - bb, u00, u10);
            const float2 sel = ((lane >> bb) & 1) ? u10 : u00;
            lp = cmul(lp, sel);
        }
        float2 v3[2], v2[2], v1[2], v0[2];          // reg bits 0..3 <-> wires 3,2,1,0
        col0(cs, 3, v3[0], v3[1]);
        col0(cs, 2, v2[0], v2[1]);
        col0(cs, 1, v1[0], v1[1]);
        col0(cs, 0, v0[0], v0[1]);
        #pragma unroll
        for (int a = 0; a < 16; ++a) {
            float2 t = cmul(v3[a & 1], v2[(a >> 1) & 1]);
            t = cmul(t, cmul(v1[(a >> 2) & 1], v0[(a >> 3) & 1]));
            st[a] = cmul(t, lp);
        }
    }

    // ---- circuit (sweep 1 already folded) ----
    ringF<0>(st, lane, cs, 30);
    ringB<NQ - 1>(st, lane, cs, 40);
    layer1q<0>(st, lane, cs, 50);
    ringF<0>(st, lane, cs, 80);
    ringB<NQ - 1>(st, lane, cs, 90);

    // ---- measurements into LDS ----
    measureAll<0>(st, lane, mloc[wv]);
    __syncthreads();

    // ---- combine: out = |alpha*m1 + beta*m2 + gamma*m3| / norm ----
    if (threadIdx.x < NOUT) {
        const int i = threadIdx.x;
        const float ar = ar_[0], ai = ai_[0];
        const float br = br_[0], bi = bi_[0];
        const float gr = gr_[0], gi = gi_[0];
        const float inv = 1.f / sqrtf(ar*ar + ai*ai + br*br + bi*bi
                                      + gr*gr + gi*gi + 1e-9f);
        const float m1 = mloc[0][i], m2 = mloc[1][i], m3 = mloc[2][i];
        const float re = (ar * m1 + br * m2 + gr * m3) * inv;
        const float im = (ai * m1 + bi * m2 + gi * m3) * inv;
        out[(size_t)b * NOUT + i] = sqrtf(re * re + im * im);
    }
}

extern "C" void kernel_launch(void* const* d_in, const int* in_sizes, int n_in,
                              void* d_out, int out_size, void* d_ws, size_t ws_size,
                              hipStream_t stream)
{
    (void)in_sizes; (void)n_in; (void)out_size; (void)d_ws; (void)ws_size;
    const float* x     = (const float*)d_in[0];
    const float* W1    = (const float*)d_in[1];
    const float* b1    = (const float*)d_in[2];
    const float* W2    = (const float*)d_in[3];
    const float* b2    = (const float*)d_in[4];
    const float* W3    = (const float*)d_in[5];
    const float* b3    = (const float*)d_in[6];
    const float* base1 = (const float*)d_in[7];
    const float* base2 = (const float*)d_in[8];
    const float* base3 = (const float*)d_in[9];
    const float* ar    = (const float*)d_in[10];
    const float* ai    = (const float*)d_in[11];
    const float* br    = (const float*)d_in[12];
    const float* bi    = (const float*)d_in[13];
    const float* gr    = (const float*)d_in[14];
    const float* gi    = (const float*)d_in[15];

    qsb_fused<<<dim3(BATCH), dim3(192), 0, stream>>>(
        x, W1, b1, base1, W2, b2, base2, W3, b3, base3,
        ar, ai, br, bi, gr, gi, (float*)d_out);
}

// Round 5
// 110.956 us; speedup vs baseline: 1.1332x; 1.0570x over previous
//
#include <hip/hip_runtime.h>
#include <math.h>

#define NQ 10
#define NPAR 100
#define FDIM 256
#define BATCH 256
#define NOUT 30
#define TWO_PI_F 6.283185307179586f

// State layout: amplitude index i (10 bits). Bits [9:6] -> register slot a (16 float2
// per lane), bits [5:0] -> lane. Wire w (PennyLane MSB-first) <-> bit (9 - w).
// Round 5: same structure as round 4 (proven 40us / passing), but cross-lane ops
// use the cheapest primitive per xor-mask:
//   mask 1,2 : DPP quad_perm   (VALU pipe, no DS round-trip)
//   mask 8   : DPP row_ror:8   (xor by half of 16-lane row == rotate by 8)
//   mask 4,16: single ds_swizzle (BitMode xor)
//   mask 32  : __shfl_xor (ds_permute pair, unavoidable across 32-lane halves)
// DS-based gates gather 4 slots (8 dwords) per group with scalar locals so the
// DS ops pipeline (arrays regressed in round 3 -> avoid).

template<int MASK>
__device__ __forceinline__ float lx(float v) {
    if constexpr (MASK == 1) {
        return __int_as_float(__builtin_amdgcn_update_dpp(
            0, __float_as_int(v), 0xB1, 0xF, 0xF, true));   // quad_perm [1,0,3,2]
    } else if constexpr (MASK == 2) {
        return __int_as_float(__builtin_amdgcn_update_dpp(
            0, __float_as_int(v), 0x4E, 0xF, 0xF, true));   // quad_perm [2,3,0,1]
    } else if constexpr (MASK == 8) {
        return __int_as_float(__builtin_amdgcn_update_dpp(
            0, __float_as_int(v), 0x128, 0xF, 0xF, true));  // row_ror:8 == xor 8
    } else if constexpr (MASK == 4) {
        return __int_as_float(__builtin_amdgcn_ds_swizzle(__float_as_int(v), 0x101F));
    } else if constexpr (MASK == 16) {
        return __int_as_float(__builtin_amdgcn_ds_swizzle(__float_as_int(v), 0x401F));
    } else {
        return __shfl_xor(v, 32, 64);
    }
}

template<int MASK>
__device__ __forceinline__ float2 lx2(float2 v) {
    return make_float2(lx<MASK>(v.x), lx<MASK>(v.y));
}

__device__ __forceinline__ float redAll(float v) {
    v += lx<1>(v);  v += lx<2>(v);  v += lx<4>(v);
    v += lx<8>(v);  v += lx<16>(v); v += lx<32>(v);
    return v;
}

__device__ __forceinline__ float2 cmul(float2 a, float2 b) {
    return make_float2(a.x*b.x - a.y*b.y, a.x*b.y + a.y*b.x);
}

// ---- fused 1-qubit gate U = Rz*Ry*Rx on bit BIT ----
template<int BIT>
__device__ __forceinline__ void gate1q(float2 (&st)[16], int lane,
                                       float2 u00, float2 u01, float2 u10, float2 u11)
{
    if constexpr (BIT >= 6) {
        constexpr int rb = 1 << (BIT - 6);
        #pragma unroll
        for (int a = 0; a < 16; ++a) {
            if (a & rb) continue;
            const int a1 = a | rb;
            const float2 A0 = st[a], A1 = st[a1];
            float2 n0, n1;
            n0.x = u00.x*A0.x - u00.y*A0.y + u01.x*A1.x - u01.y*A1.y;
            n0.y = u00.x*A0.y + u00.y*A0.x + u01.x*A1.y + u01.y*A1.x;
            n1.x = u10.x*A0.x - u10.y*A0.y + u11.x*A1.x - u11.y*A1.y;
            n1.y = u10.x*A0.y + u10.y*A0.x + u11.x*A1.y + u11.y*A1.x;
            st[a] = n0; st[a1] = n1;
        }
    } else {
        constexpr int lb = 1 << BIT;
        const bool hi = (lane & lb) != 0;
        const float2 A = hi ? u11 : u00;
        const float2 B = hi ? u10 : u01;
        #pragma unroll
        for (int g = 0; g < 16; g += 4) {
            const float2 p0 = lx2<lb>(st[g+0]);
            const float2 p1 = lx2<lb>(st[g+1]);
            const float2 p2 = lx2<lb>(st[g+2]);
            const float2 p3 = lx2<lb>(st[g+3]);
            const float2 m0 = st[g+0], m1 = st[g+1], m2 = st[g+2], m3 = st[g+3];
            st[g+0] = make_float2(A.x*m0.x - A.y*m0.y + B.x*p0.x - B.y*p0.y,
                                  A.x*m0.y + A.y*m0.x + B.x*p0.y + B.y*p0.x);
            st[g+1] = make_float2(A.x*m1.x - A.y*m1.y + B.x*p1.x - B.y*p1.y,
                                  A.x*m1.y + A.y*m1.x + B.x*p1.y + B.y*p1.x);
            st[g+2] = make_float2(A.x*m2.x - A.y*m2.y + B.x*p2.x - B.y*p2.y,
                                  A.x*m2.y + A.y*m2.x + B.x*p2.y + B.y*p2.x);
            st[g+3] = make_float2(A.x*m3.x - A.y*m3.y + B.x*p3.x - B.y*p3.y,
                                  A.x*m3.y + A.y*m3.x + B.x*p3.y + B.y*p3.x);
        }
    }
}

// ---- CRX(theta) control bit BC, target bit BT; c=cos(t/2), s=sin(t/2) ----
template<int BC, int BT>
__device__ __forceinline__ void crx(float2 (&st)[16], int lane, float c, float s)
{
    if constexpr (BT >= 6) {
        constexpr int rt = 1 << (BT - 6);
        if constexpr (BC >= 6) {
            constexpr int rc = 1 << (BC - 6);
            #pragma unroll
            for (int a = 0; a < 16; ++a) {
                if (!(a & rc) || (a & rt)) continue;
                const int a1 = a | rt;
                const float2 A0 = st[a], A1 = st[a1];
                float2 n0, n1;
                n0.x = c*A0.x + s*A1.y;  n0.y = c*A0.y - s*A1.x;
                n1.x = c*A1.x + s*A0.y;  n1.y = c*A1.y - s*A0.x;
                st[a] = n0; st[a1] = n1;
            }
        } else {
            constexpr int lc = 1 << BC;
            const bool act = (lane & lc) != 0;
            const float cc = act ? c : 1.f;
            const float ss = act ? s : 0.f;
            #pragma unroll
            for (int a = 0; a < 16; ++a) {
                if (a & rt) continue;
                const int a1 = a | rt;
                const float2 A0 = st[a], A1 = st[a1];
                float2 n0, n1;
                n0.x = cc*A0.x + ss*A1.y;  n0.y = cc*A0.y - ss*A1.x;
                n1.x = cc*A1.x + ss*A0.y;  n1.y = cc*A1.y - ss*A0.x;
                st[a] = n0; st[a1] = n1;
            }
        }
    } else {
        constexpr int lt = 1 << BT;
        if constexpr (BC >= 6) {
            // register-bit control: only 8 active slots (a & rc), grouped 4
            constexpr int rc = 1 << (BC - 6);
            #pragma unroll
            for (int j = 0; j < 8; j += 4) {
                const int a0 = ((j     & ~(rc-1)) << 1) | rc | ((j  ) & (rc-1));
                const int a1 = (((j+1) & ~(rc-1)) << 1) | rc | ((j+1) & (rc-1));
                const int a2 = (((j+2) & ~(rc-1)) << 1) | rc | ((j+2) & (rc-1));
                const int a3 = (((j+3) & ~(rc-1)) << 1) | rc | ((j+3) & (rc-1));
                const float2 p0 = lx2<lt>(st[a0]);
                const float2 p1 = lx2<lt>(st[a1]);
                const float2 p2 = lx2<lt>(st[a2]);
                const float2 p3 = lx2<lt>(st[a3]);
                const float2 m0 = st[a0], m1 = st[a1], m2 = st[a2], m3 = st[a3];
                st[a0] = make_float2(c*m0.x + s*p0.y, c*m0.y - s*p0.x);
                st[a1] = make_float2(c*m1.x + s*p1.y, c*m1.y - s*p1.x);
                st[a2] = make_float2(c*m2.x + s*p2.y, c*m2.y - s*p2.x);
                st[a3] = make_float2(c*m3.x + s*p3.y, c*m3.y - s*p3.x);
            }
        } else {
            constexpr int lc = 1 << BC;
            const bool act = (lane & lc) != 0;
            const float cc = act ? c : 1.f;
            const float ss = act ? s : 0.f;
            #pragma unroll
            for (int g = 0; g < 16; g += 4) {
                const float2 p0 = lx2<lt>(st[g+0]);
                const float2 p1 = lx2<lt>(st[g+1]);
                const float2 p2 = lx2<lt>(st[g+2]);
                const float2 p3 = lx2<lt>(st[g+3]);
                const float2 m0 = st[g+0], m1 = st[g+1], m2 = st[g+2], m3 = st[g+3];
                st[g+0] = make_float2(cc*m0.x + ss*p0.y, cc*m0.y - ss*p0.x);
                st[g+1] = make_float2(cc*m1.x + ss*p1.y, cc*m1.y - ss*p1.x);
                st[g+2] = make_float2(cc*m2.x + ss*p2.y, cc*m2.y - ss*p2.x);
                st[g+3] = make_float2(cc*m3.x + ss*p3.y, cc*m3.y - ss*p3.x);
            }
        }
    }
}

// ---- recursive circuit drivers (compile-time q) ----
template<int Q>
__device__ __forceinline__ void layer1q(float2 (&st)[16], int lane, const float2* cs, int idx)
{
    if constexpr (Q < NQ) {
        const float2 X = cs[idx], Y = cs[idx + 1], Z = cs[idx + 2];
        const float cx = X.x, sx = X.y, cy = Y.x, sy = Y.y, cz = Z.x, sz = Z.y;
        const float2 m00 = make_float2( cy*cx,  sy*sx);
        const float2 m01 = make_float2(-sy*cx, -cy*sx);
        const float2 m10 = make_float2( sy*cx, -cy*sx);
        const float2 m11 = make_float2( cy*cx, -sy*sx);
        const float2 u00 = make_float2(cz*m00.x + sz*m00.y, cz*m00.y - sz*m00.x);
        const float2 u01 = make_float2(cz*m01.x + sz*m01.y, cz*m01.y - sz*m01.x);
        const float2 u10 = make_float2(cz*m10.x - sz*m10.y, cz*m10.y + sz*m10.x);
        const float2 u11 = make_float2(cz*m11.x - sz*m11.y, cz*m11.y + sz*m11.x);
        gate1q<9 - Q>(st, lane, u00, u01, u10, u11);
        layer1q<Q + 1>(st, lane, cs, idx + 3);
    }
}

template<int Q>
__device__ __forceinline__ void ringF(float2 (&st)[16], int lane, const float2* cs, int idx)
{
    if constexpr (Q < NQ) {
        const float2 p = cs[idx];
        crx<9 - Q, 9 - ((Q + 1) % NQ)>(st, lane, p.x, p.y);
        ringF<Q + 1>(st, lane, cs, idx + 1);
    }
}

template<int Q>
__device__ __forceinline__ void ringB(float2 (&st)[16], int lane, const float2* cs, int idx)
{
    if constexpr (Q >= 0) {
        const float2 p = cs[idx];
        crx<9 - Q, 9 - ((Q + NQ - 1) % NQ)>(st, lane, p.x, p.y);
        ringB<Q - 1>(st, lane, cs, idx + 1);
    }
}

// ---- column 0 of fused U = Rz*Ry*Rx (product-state init; verified rounds 3-4) ----
__device__ __forceinline__ void col0(const float2* cs, int w, float2& u00, float2& u10)
{
    const float2 X = cs[3*w], Y = cs[3*w + 1], Z = cs[3*w + 2];
    const float cx = X.x, sx = X.y, cy = Y.x, sy = Y.y, cz = Z.x, sz = Z.y;
    const float2 m00 = make_float2(cy*cx,  sy*sx);
    const float2 m10 = make_float2(sy*cx, -cy*sx);
    u00 = make_float2(cz*m00.x + sz*m00.y, cz*m00.y - sz*m00.x);
    u10 = make_float2(cz*m10.x - sz*m10.y, cz*m10.y + sz*m10.x);
}

// ---- measurements ----
template<int W>
__device__ __forceinline__ void measureAll(const float2 (&st)[16], int lane, float* m_row)
{
    if constexpr (W < NQ) {
        constexpr int B = 9 - W;
        float sre = 0.f, smm = 0.f, szz = 0.f;
        if constexpr (B >= 6) {
            constexpr int rb = 1 << (B - 6);
            #pragma unroll
            for (int a = 0; a < 16; ++a) {
                if (a & rb) continue;
                const int a1 = a | rb;
                const float2 A0 = st[a], A1 = st[a1];
                sre += A0.x*A1.x + A0.y*A1.y;
                smm += A0.x*A1.y - A0.y*A1.x;
                szz += A0.x*A0.x + A0.y*A0.y - A1.x*A1.x - A1.y*A1.y;
            }
            sre *= 2.f; smm *= 2.f;
        } else {
            constexpr int lb = 1 << B;
            const float sgn = (lane & lb) ? -1.f : 1.f;
            #pragma unroll
            for (int g = 0; g < 16; g += 4) {
                const float2 p0 = lx2<lb>(st[g+0]);
                const float2 p1 = lx2<lb>(st[g+1]);
                const float2 p2 = lx2<lb>(st[g+2]);
                const float2 p3 = lx2<lb>(st[g+3]);
                const float2 m0 = st[g+0], m1 = st[g+1], m2 = st[g+2], m3 = st[g+3];
                sre += m0.x*p0.x + m0.y*p0.y + m1.x*p1.x + m1.y*p1.y
                     + m2.x*p2.x + m2.y*p2.y + m3.x*p3.x + m3.y*p3.y;
                smm += sgn * ((m0.x*p0.y - m0.y*p0.x) + (m1.x*p1.y - m1.y*p1.x)
                            + (m2.x*p2.y - m2.y*p2.x) + (m3.x*p3.y - m3.y*p3.x));
                szz += sgn * ((m0.x*m0.x + m0.y*m0.y - p0.x*p0.x - p0.y*p0.y)
                            + (m1.x*m1.x + m1.y*m1.y - p1.x*p1.x - p1.y*p1.y)
                            + (m2.x*m2.x + m2.y*m2.y - p2.x*p2.x - p2.y*p2.y)
                            + (m3.x*m3.x + m3.y*m3.y - p3.x*p3.x - p3.y*p3.y));
            }
            szz *= 0.5f;
        }
        sre = redAll(sre);
        smm = redAll(smm);
        szz = redAll(szz);
        if (lane == 0) {
            m_row[W]      = sre;
            m_row[10 + W] = smm;
            m_row[20 + W] = szz;
        }
        measureAll<W + 1>(st, lane, m_row);
    }
}

__global__ __launch_bounds__(192) void qsb_fused(
    const float* __restrict__ x,
    const float* __restrict__ W1, const float* __restrict__ b1, const float* __restrict__ base1,
    const float* __restrict__ W2, const float* __restrict__ b2, const float* __restrict__ base2,
    const float* __restrict__ W3, const float* __restrict__ b3, const float* __restrict__ base3,
    const float* __restrict__ ar_, const float* __restrict__ ai_,
    const float* __restrict__ br_, const float* __restrict__ bi_,
    const float* __restrict__ gr_, const float* __restrict__ gi_,
    float* __restrict__ out)
{
    const int b    = blockIdx.x;             // batch item
    const int wv   = threadIdx.x >> 6;       // branch 0..2 (one wave each)
    const int lane = threadIdx.x & 63;

    const float* W    = (wv == 0) ? W1    : (wv == 1) ? W2    : W3;
    const float* bias = (wv == 0) ? b1    : (wv == 1) ? b2    : b3;
    const float* base = (wv == 0) ? base1 : (wv == 1) ? base2 : base3;

    __shared__ float2 css[3][NPAR];
    __shared__ float  mloc[3][NOUT];
    float2* cs = css[wv];

    // ---- params: p = sigmoid(x.W^T + bias + base) * 2pi ; store (cos,sin)(p/2) ----
    if (lane < 50) {
        const int p0 = 2 * lane;
        const float4* xr = reinterpret_cast<const float4*>(x + (size_t)b * FDIM);
        const float4* w0 = reinterpret_cast<const float4*>(W + (size_t)p0 * FDIM);
        const float4* w1 = reinterpret_cast<const float4*>(W + (size_t)(p0 + 1) * FDIM);
        float acc0 = 0.f, acc1 = 0.f;
        #pragma unroll 8
        for (int k = 0; k < FDIM / 4; ++k) {
            const float4 xv = xr[k];
            const float4 a  = w0[k];
            const float4 bb = w1[k];
            acc0 += xv.x*a.x  + xv.y*a.y  + xv.z*a.z  + xv.w*a.w;
            acc1 += xv.x*bb.x + xv.y*bb.y + xv.z*bb.z + xv.w*bb.w;
        }
        acc0 += bias[p0]     + base[p0];
        acc1 += bias[p0 + 1] + base[p0 + 1];
        const float t0 = TWO_PI_F / (1.f + __expf(-acc0));
        const float t1 = TWO_PI_F / (1.f + __expf(-acc1));
        float s0, c0, s1, c1;
        __sincosf(0.5f * t0, &s0, &c0);
        __sincosf(0.5f * t1, &s1, &c1);
        cs[p0]     = make_float2(c0, s0);
        cs[p0 + 1] = make_float2(c1, s1);
    }
    __syncthreads();

    // ---- sweep 1 folded into product-state init ----
    float2 st[16];
    {
        float2 lp = make_float2(1.f, 0.f);
        #pragma unroll
        for (int bb = 0; bb < 6; ++bb) {            // lane bit bb <-> wire 9-bb
            float2 u00, u10;
            col0(cs, 9 - bb, u00, u10);
            const float2 sel = ((lane >> bb) & 1) ? u10 : u00;
            lp = cmul(lp, sel);
        }
        float2 v3[2], v2[2], v1[2], v0[2];          // reg bits 0..3 <-> wires 3,2,1,0
        col0(cs, 3, v3[0], v3[1]);
        col0(cs, 2, v2[0], v2[1]);
        col0(cs, 1, v1[0], v1[1]);
        col0(cs, 0, v0[0], v0[1]);
        #pragma unroll
        for (int a = 0; a < 16; ++a) {
            float2 t = cmul(v3[a & 1], v2[(a >> 1) & 1]);
            t = cmul(t, cmul(v1[(a >> 2) & 1], v0[(a >> 3) & 1]));
            st[a] = cmul(t, lp);
        }
    }

    // ---- circuit (sweep 1 already folded) ----
    ringF<0>(st, lane, cs, 30);
    ringB<NQ - 1>(st, lane, cs, 40);
    layer1q<0>(st, lane, cs, 50);
    ringF<0>(st, lane, cs, 80);
    ringB<NQ - 1>(st, lane, cs, 90);

    // ---- measurements into LDS ----
    measureAll<0>(st, lane, mloc[wv]);
    __syncthreads();

    // ---- combine: out = |alpha*m1 + beta*m2 + gamma*m3| / norm ----
    if (threadIdx.x < NOUT) {
        const int i = threadIdx.x;
        const float ar = ar_[0], ai = ai_[0];
        const float br = br_[0], bi = bi_[0];
        const float gr = gr_[0], gi = gi_[0];
        const float inv = 1.f / sqrtf(ar*ar + ai*ai + br*br + bi*bi
                                      + gr*gr + gi*gi + 1e-9f);
        const float m1 = mloc[0][i], m2 = mloc[1][i], m3 = mloc[2][i];
        const float re = (ar * m1 + br * m2 + gr * m3) * inv;
        const float im = (ai * m1 + bi * m2 + gi * m3) * inv;
        out[(size_t)b * NOUT + i] = sqrtf(re * re + im * im);
    }
}

extern "C" void kernel_launch(void* const* d_in, const int* in_sizes, int n_in,
                              void* d_out, int out_size, void* d_ws, size_t ws_size,
                              hipStream_t stream)
{
    (void)in_sizes; (void)n_in; (void)out_size; (void)d_ws; (void)ws_size;
    const float* x     = (const float*)d_in[0];
    const float* W1    = (const float*)d_in[1];
    const float* b1    = (const float*)d_in[2];
    const float* W2    = (const float*)d_in[3];
    const float* b2    = (const float*)d_in[4];
    const float* W3    = (const float*)d_in[5];
    const float* b3    = (const float*)d_in[6];
    const float* base1 = (const float*)d_in[7];
    const float* base2 = (const float*)d_in[8];
    const float* base3 = (const float*)d_in[9];
    const float* ar    = (const float*)d_in[10];
    const float* ai    = (const float*)d_in[11];
    const float* br    = (const float*)d_in[12];
    const float* bi    = (const float*)d_in[13];
    const float* gr    = (const float*)d_in[14];
    const float* gi    = (const float*)d_in[15];

    qsb_fused<<<dim3(BATCH), dim3(192), 0, stream>>>(
        x, W1, b1, base1, W2, b2, base2, W3, b3, base3,
        ar, ai, br, bi, gr, gi, (float*)d_out);
}